// Round 8
// baseline (16068.846 us; speedup 1.0000x reference)
//
#include <hip/hip_runtime.h>
#include <hip/hip_bf16.h>

// LSTM decoder: B=256, H=1024, L=2, T=128.
// R8: R7 cohort kernel with the spill fixed. __launch_bounds__ second arg is
// min BLOCKS/CU (CUDA semantics — R6/R7 counter evidence): (512,2) capped
// VGPRs at 128 and spilled the 128-reg A-array; (512,1) gives 2 waves/SIMD
// and a 256-VGPR cap, so the per-wave A-slice (2 gates x 512 K = 128 VGPRs)
// is truly register-resident. Structure unchanged from R7: 256 blocks =
// layer(2) x bh(2) x jc(64); 512 threads; stamp gates between unrolled
// h/x subloops; LDS kq-partial reduce; fused LSTM epilogue.

typedef _Float16 half8 __attribute__((ext_vector_type(8)));
typedef _Float16 half4 __attribute__((ext_vector_type(4)));
typedef float f32x4 __attribute__((ext_vector_type(4)));

#define HSZ 1024
#define BSZ 256
#define TSZ 128

// ---------------- prep: vraw = W^T u (two-stage deterministic) ----------------
__global__ __launch_bounds__(256) void prep_vraw1(
    const float* __restrict__ Wih, const float* __restrict__ Whh,
    const float* __restrict__ uih, const float* __restrict__ uhh,
    float* __restrict__ vpart) {
  int bx = blockIdx.x;                 // 256 blocks: m(4) x rc(16) x jc(4)
  int m = bx >> 6, rc = (bx >> 2) & 15, jc = bx & 3;
  int j = jc * 256 + threadIdx.x;
  const float* W = (m < 2 ? Wih : Whh) + ((size_t)(m & 1) << 22);
  const float* u = (m < 2 ? uih : uhh) + (m & 1) * 4096;
  float acc = 0.f;
  int rbase = rc * 256;
  for (int r = 0; r < 256; ++r)
    acc += W[(size_t)(rbase + r) * 1024 + j] * u[rbase + r];
  vpart[(m * 16 + rc) * 1024 + j] = acc;
}

__global__ __launch_bounds__(256) void prep_vraw2(
    const float* __restrict__ vpart, float* __restrict__ vraw) {
  int i = blockIdx.x * 256 + threadIdx.x;   // 0..4095 -> m*1024+j
  int m = i >> 10;
  float acc = 0.f;
  for (int rc = 0; rc < 16; ++rc)
    acc += vpart[(m * 16 + rc) * 1024 + (i & 1023)];
  vraw[i] = acc;
}

// ---------------- prep: wv = W @ vraw ----------------
__global__ __launch_bounds__(256) void prep_wv(
    const float* __restrict__ Wih, const float* __restrict__ Whh,
    const float* __restrict__ vraw, float* __restrict__ wv) {
  int m = blockIdx.y;
  int w = threadIdx.x >> 6, l = threadIdx.x & 63;
  int r = blockIdx.x * 4 + w;
  const float* W = (m < 2 ? Wih : Whh) + ((size_t)(m & 1) << 22) + (size_t)r * 1024;
  const float* v = vraw + m * 1024;
  float acc = 0.f;
  for (int it = 0; it < 4; ++it) {
    int j = it * 256 + l * 4;
    float4 w4 = *(const float4*)(W + j);
    float4 v4 = *(const float4*)(v + j);
    acc += w4.x * v4.x + w4.y * v4.y + w4.z * v4.z + w4.w * v4.w;
  }
  for (int o = 32; o; o >>= 1) acc += __shfl_down(acc, o);
  if (l == 0) wv[m * 4096 + r] = acc;
}

// ---------------- prep: inv_sigma = ||vraw|| / ||wv|| ----------------
__global__ __launch_bounds__(256) void prep_sig(
    const float* __restrict__ vraw, const float* __restrict__ wv,
    float* __restrict__ invsig) {
  int m = blockIdx.x, tid = threadIdx.x;
  __shared__ float red[256];
  float sv = 0.f, sw = 0.f;
  for (int i = tid; i < 1024; i += 256) { float x = vraw[m * 1024 + i]; sv += x * x; }
  for (int i = tid; i < 4096; i += 256) { float x = wv[m * 4096 + i]; sw += x * x; }
  red[tid] = sv; __syncthreads();
  for (int s = 128; s; s >>= 1) { if (tid < s) red[tid] += red[tid + s]; __syncthreads(); }
  float svt = red[0]; __syncthreads();
  red[tid] = sw; __syncthreads();
  for (int s = 128; s; s >>= 1) { if (tid < s) red[tid] += red[tid + s]; __syncthreads(); }
  if (tid == 0) invsig[m] = sqrtf(svt / red[0]);
}

// ---------------- prep: fragment-packed A (f16, scaled) ----------------
// granule id = ((((layer*64+jc)*8 + w)*32 + (m_local*16+s))*64 + lane), 16 B.
// wave w: kq = w&3 (K-quarter), mh = w>>2 (gate-half). gate = mh*2+m_local.
// k(s) = s<8 ? 1024 + kq*256 + s*32 : kq*256 + (s-8)*32  (+ (lane>>4)*8).
// row = gate*1024 + jc*16 + (lane&15).
__global__ __launch_bounds__(256) void prep_apack(
    const float* __restrict__ Wih, const float* __restrict__ Whh,
    const float* __restrict__ invsig, _Float16* __restrict__ apack) {
  unsigned id = blockIdx.x * 256 + threadIdx.x;   // 0 .. 2^21-1
  int lane = id & 63, f = (id >> 6) & 31, w = (id >> 11) & 7;
  int jc = (id >> 14) & 63, layer = (id >> 20) & 1;
  int kq = w & 3, mh = w >> 2;
  int m_local = f >> 4, s = f & 15;
  int gate = mh * 2 + m_local;
  int lr = lane & 15, lk = lane >> 4;
  int row = gate * 1024 + jc * 16 + lr;
  int k = (s < 8) ? (1024 + kq * 256 + s * 32 + lk * 8)
                  : (kq * 256 + (s - 8) * 32 + lk * 8);
  const float* src; float sc;
  if (k < 1024) {
    src = Wih + ((size_t)layer << 22) + (size_t)row * 1024 + k;
    sc = invsig[layer];
  } else {
    src = Whh + ((size_t)layer << 22) + (size_t)row * 1024 + (k - 1024);
    sc = invsig[2 + layer];
  }
  float4 v0 = *(const float4*)src;
  float4 v1 = *(const float4*)(src + 4);
  half8 o = { (_Float16)(v0.x * sc), (_Float16)(v0.y * sc),
              (_Float16)(v0.z * sc), (_Float16)(v0.w * sc),
              (_Float16)(v1.x * sc), (_Float16)(v1.y * sc),
              (_Float16)(v1.z * sc), (_Float16)(v1.w * sc) };
  *(half8*)(apack + (size_t)id * 8) = o;
}

__global__ __launch_bounds__(256) void prep_bias(
    const float* __restrict__ b_ih, const float* __restrict__ b_hh,
    float* __restrict__ bias) {
  int i = blockIdx.x * 256 + threadIdx.x;
  if (i < 8192) bias[i] = b_ih[i] + b_hh[i];
}

__global__ __launch_bounds__(256) void prep_init(
    const float* __restrict__ x0, const float* __restrict__ h0,
    const float* __restrict__ c0, _Float16* __restrict__ Xinit,
    _Float16* __restrict__ H0p0, _Float16* __restrict__ H1p0,
    float* __restrict__ C0, float* __restrict__ C1) {
  int i = blockIdx.x * 256 + threadIdx.x;   // 0..262143
  Xinit[i] = (_Float16)x0[i];
  H0p0[i]  = (_Float16)h0[i];
  H1p0[i]  = (_Float16)h0[262144 + i];
  C0[i] = c0[i];
  C1[i] = c0[262144 + i];
}

// ---------------- stamp gate: per-jc stamps, ballot poll ----------------
static __device__ __forceinline__ void wait_ge(const unsigned* a, int lane, int tgt) {
  unsigned v = __hip_atomic_load(a + lane, __ATOMIC_RELAXED, __HIP_MEMORY_SCOPE_AGENT);
  while (__any(v < (unsigned)tgt)) {
    __builtin_amdgcn_s_sleep(2);
    v = __hip_atomic_load(a + lane, __ATOMIC_RELAXED, __HIP_MEMORY_SCOPE_AGENT);
  }
  __builtin_amdgcn_fence(__ATOMIC_ACQUIRE, "agent");   // invalidate stale caches
}

// ---------------- the persistent cohort kernel ----------------
__global__ __launch_bounds__(512, 1) void lstm_cohort8(
    const _Float16* __restrict__ Apack, const float* __restrict__ bias,
    const _Float16* __restrict__ Xinit,
    _Float16* __restrict__ H00, _Float16* __restrict__ H01,
    _Float16* __restrict__ H10, _Float16* __restrict__ H11,
    float* __restrict__ C0, float* __restrict__ C1,
    float* __restrict__ out, unsigned* __restrict__ arr) {
  __shared__ float part[4][64][66];   // [kq][gate-row][batch col +pad]
  const int tid = threadIdx.x, lane = tid & 63, w = tid >> 6;
  const int lr = lane & 15, lk = lane >> 4;
  const int kq = w & 3, mh = w >> 2;
  const int bx = blockIdx.x;
  const int layer = bx & 1, bh = (bx >> 1) & 1, jc = bx >> 2;
  const int j0 = jc * 16, bm0 = bh * 128;

  // ---- A prologue: this wave's K-slice, 128 VGPRs, resident for the run
  half8 a[2][16];
  {
    const _Float16* ab = Apack +
        ((size_t)(((layer * 64 + jc) * 8 + w) * 32) * 64 + lane) * 8;
#pragma unroll
    for (int m = 0; m < 2; ++m)
#pragma unroll
      for (int s = 0; s < 16; ++s)
        a[m][s] = *(const half8*)(ab + (size_t)(m * 16 + s) * 512);
  }

  float* cb = layer ? C1 : C0;
  const float* bs = bias + layer * 4096;
  unsigned* own = arr + (layer * 2 + bh) * 64;
  unsigned* oth = arr + ((1 - layer) * 2 + bh) * 64;

  // epilogue bias preload: thread covers h-cols {rr, rr+8}, rr = tid>>6
  const int rr = tid >> 6, bcol = tid & 63;
  float breg[4][2];
#pragma unroll
  for (int g = 0; g < 4; ++g) {
    breg[g][0] = bs[g * 1024 + j0 + rr];
    breg[g][1] = bs[g * 1024 + j0 + rr + 8];
  }

#pragma unroll 1
  for (int t = 0; t < TSZ; ++t) {
    const int p = t & 1;
    const _Float16* hb = layer ? (p ? H11 : H10) : (p ? H01 : H00);
    const _Float16* xb = layer ? (p ? H00 : H01)
                               : (t == 0 ? Xinit : (p ? H11 : H10));
    _Float16* hw = layer ? (p ? H10 : H11) : (p ? H00 : H01);

    // h-gate: own cohort finished cell t-1
    if (t) wait_ge(own, lane, t);

#define LH(S, BUF) do { _Pragma("unroll")                                     \
    for (int n = 0; n < 4; ++n)                                               \
      bb[BUF][n] = *(const half8*)(hb + ro[n] + kq * 256 + (S) * 32);         \
  } while (0)
#define LX(S, BUF) do { _Pragma("unroll")                                     \
    for (int n = 0; n < 4; ++n)                                               \
      bb[BUF][n] = *(const half8*)(xb + ro[n] + kq * 256 + ((S) - 8) * 32);   \
  } while (0)
#define MF(S, BUF) do { _Pragma("unroll")                                     \
    for (int m = 0; m < 2; ++m) { _Pragma("unroll")                           \
      for (int n = 0; n < 4; ++n)                                             \
        acc[m][n] = __builtin_amdgcn_mfma_f32_16x16x32_f16(                   \
            a[m][S], bb[BUF][n], acc[m][n], 0, 0, 0); }                       \
  } while (0)

#define PASS(NH, GATED) do {                                                  \
    unsigned ro[4];                                                           \
    _Pragma("unroll")                                                         \
    for (int n = 0; n < 4; ++n)                                               \
      ro[n] = (unsigned)(bm0 + (NH) * 64 + n * 16 + lr) * 1024 + lk * 8;      \
    f32x4 acc[2][4];                                                          \
    _Pragma("unroll")                                                         \
    for (int m = 0; m < 2; ++m) { _Pragma("unroll")                           \
      for (int n = 0; n < 4; ++n) acc[m][n] = (f32x4){0.f, 0.f, 0.f, 0.f}; }  \
    half8 bb[2][4];                                                           \
    /* h-subloop: K-tiles 0..7 (state from t-1, covered by h-gate) */         \
    LH(0, 0); LH(1, 1);                                                       \
    MF(0, 0); LH(2, 0);                                                       \
    MF(1, 1); LH(3, 1);                                                       \
    MF(2, 0); LH(4, 0);                                                       \
    MF(3, 1); LH(5, 1);                                                       \
    MF(4, 0); LH(6, 0);                                                       \
    MF(5, 1); LH(7, 1);                                                       \
    MF(6, 0); MF(7, 1);                                                       \
    /* x-gate (outside any unrolled loop; only pass 0 needs it) */            \
    if ((GATED) && !(layer == 0 && t == 0)) wait_ge(oth, lane, t + layer);    \
    /* x-subloop: K-tiles 8..15 */                                            \
    LX(8, 0); LX(9, 1);                                                       \
    MF(8, 0); LX(10, 0);                                                      \
    MF(9, 1); LX(11, 1);                                                      \
    MF(10, 0); LX(12, 0);                                                     \
    MF(11, 1); LX(13, 1);                                                     \
    MF(12, 0); LX(14, 0);                                                     \
    MF(13, 1); LX(15, 1);                                                     \
    MF(14, 0); MF(15, 1);                                                     \
    /* partials -> LDS (2-way bank aliasing max = free) */                    \
    _Pragma("unroll")                                                         \
    for (int m = 0; m < 2; ++m) { _Pragma("unroll")                           \
      for (int n = 0; n < 4; ++n) { _Pragma("unroll")                         \
        for (int j = 0; j < 4; ++j)                                           \
          part[kq][mh * 32 + m * 16 + lk * 4 + j][n * 16 + lr] =              \
              acc[m][n][j]; } }                                               \
    __syncthreads();                                                          \
    /* reduce 4 kq partials + fused LSTM epilogue (2 outputs/thread) */       \
    _Pragma("unroll")                                                         \
    for (int ri = 0; ri < 2; ++ri) {                                          \
      const int rv = rr + 8 * ri;                                             \
      float gi = part[0][rv][bcol] + part[1][rv][bcol] +                      \
                 part[2][rv][bcol] + part[3][rv][bcol] + breg[0][ri];         \
      float gf = part[0][16 + rv][bcol] + part[1][16 + rv][bcol] +            \
                 part[2][16 + rv][bcol] + part[3][16 + rv][bcol] + breg[1][ri];\
      float gg = part[0][32 + rv][bcol] + part[1][32 + rv][bcol] +            \
                 part[2][32 + rv][bcol] + part[3][32 + rv][bcol] + breg[2][ri];\
      float go = part[0][48 + rv][bcol] + part[1][48 + rv][bcol] +            \
                 part[2][48 + rv][bcol] + part[3][48 + rv][bcol] + breg[3][ri];\
      const size_t idx = (size_t)(bm0 + (NH) * 64 + bcol) * 1024 + j0 + rv;   \
      float si = 1.f / (1.f + __expf(-gi));                                   \
      float sf = 1.f / (1.f + __expf(-gf));                                   \
      float so = 1.f / (1.f + __expf(-go));                                   \
      float e2g = __expf(fminf(fmaxf(2.f * gg, -30.f), 30.f));                \
      float tg = (e2g - 1.f) / (e2g + 1.f);                                   \
      float cv = sf * cb[idx] + si * tg;                                      \
      float e2c = __expf(fminf(fmaxf(2.f * cv, -30.f), 30.f));                \
      float tc = (e2c - 1.f) / (e2c + 1.f);                                   \
      cb[idx] = cv;                                                           \
      float hn = so * tc;                                                     \
      hw[idx] = (_Float16)hn;                                                 \
      if (layer)                                                              \
        out[(size_t)(bm0 + (NH) * 64 + bcol) * (TSZ * HSZ) + (size_t)t * HSZ  \
            + j0 + rv] = hn;                                                  \
    }                                                                         \
    __syncthreads();                                                          \
  } while (0)

    PASS(0, 1);
    PASS(1, 0);

#undef LH
#undef LX
#undef MF
#undef PASS

    // publish: __syncthreads drained every wave's stores to L2; release
    // store (wbl2) makes them agent-visible.
    if (tid == 0)
      __hip_atomic_store(own + jc, (unsigned)(t + 1),
                         __ATOMIC_RELEASE, __HIP_MEMORY_SCOPE_AGENT);
  }
}

extern "C" void kernel_launch(void* const* d_in, const int* in_sizes, int n_in,
                              void* d_out, int out_size, void* d_ws, size_t ws_size,
                              hipStream_t stream) {
  (void)in_sizes; (void)n_in; (void)out_size; (void)ws_size;
  const float* x0   = (const float*)d_in[0];
  const float* h0   = (const float*)d_in[1];
  const float* c0   = (const float*)d_in[2];
  const float* Wih  = (const float*)d_in[3];
  const float* Whh  = (const float*)d_in[4];
  const float* b_ih = (const float*)d_in[5];
  const float* b_hh = (const float*)d_in[6];
  const float* u_ih = (const float*)d_in[7];
  const float* u_hh = (const float*)d_in[8];
  float* out = (float*)d_out;

  char* ws = (char*)d_ws;
  size_t off = 0;
  auto alloc = [&](size_t bytes) -> void* {
    void* p = ws + off;
    off = (off + bytes + 255) & ~(size_t)255;
    return p;
  };
  _Float16* apack  = (_Float16*)alloc((size_t)2 * 4096 * 2048 * 2);
  float*    vpart  = (float*)alloc((size_t)4 * 16 * 1024 * 4);
  float*    vraw   = (float*)alloc((size_t)4 * 1024 * 4);
  float*    wv     = (float*)alloc((size_t)4 * 4096 * 4);
  float*    invsig = (float*)alloc(16);
  float*    bias   = (float*)alloc((size_t)2 * 4096 * 4);
  _Float16* Xinit  = (_Float16*)alloc((size_t)262144 * 2);
  _Float16* Hb[2][2];
  for (int a = 0; a < 2; ++a)
    for (int p = 0; p < 2; ++p)
      Hb[a][p] = (_Float16*)alloc((size_t)262144 * 2);
  float* Cb[2];
  Cb[0] = (float*)alloc((size_t)262144 * 4);
  Cb[1] = (float*)alloc((size_t)262144 * 4);
  unsigned* arr = (unsigned*)alloc(4 * 64 * sizeof(unsigned));

  prep_vraw1<<<256, 256, 0, stream>>>(Wih, Whh, u_ih, u_hh, vpart);
  prep_vraw2<<<16, 256, 0, stream>>>(vpart, vraw);
  prep_wv<<<dim3(1024, 4), 256, 0, stream>>>(Wih, Whh, vraw, wv);
  prep_sig<<<4, 256, 0, stream>>>(vraw, wv, invsig);
  prep_apack<<<8192, 256, 0, stream>>>(Wih, Whh, invsig, apack);
  prep_bias<<<32, 256, 0, stream>>>(b_ih, b_hh, bias);
  prep_init<<<1024, 256, 0, stream>>>(x0, h0, c0, Xinit, Hb[0][0], Hb[1][0], Cb[0], Cb[1]);
  hipMemsetAsync(arr, 0, 4 * 64 * sizeof(unsigned), stream);

  lstm_cohort8<<<dim3(256), dim3(512), 0, stream>>>(
      apack, bias, Xinit, Hb[0][0], Hb[0][1], Hb[1][0], Hb[1][1],
      Cb[0], Cb[1], out, arr);
}

// Round 9
// 15969.365 us; speedup vs baseline: 1.0062x; 1.0062x over previous
//
#include <hip/hip_runtime.h>
#include <hip/hip_bf16.h>

// LSTM decoder: B=256, H=1024, L=2, T=128.
// R9: R7/R8 cohort kernel with the REAL spill fix. Evidence: R7 (512,2) and
// R8 (512,1) both compiled to VGPR_Count=128 — the allocator targets the
// LDS-derived max occupancy (67.5KB -> 2 blocks/CU -> 4 waves/EU -> 128 cap)
// and spills the 128-reg A-array to reach it, even though grid=256 means only
// 1 block/CU ever runs. Fix: amdgpu_waves_per_eu(2,2) clamps the target to
// 2 waves/EU (256-VGPR budget), and LDS is grown past 80KB (part[5]..., 5th
// slice unused) so the derived max occupancy is 1 block/CU anyway.
// Structure unchanged: 256 blocks = layer(2) x bh(2) x jc(64); 512 threads;
// per-wave A-slice (2 gates x 512 K = 128 VGPRs) register-resident; stamp
// gates between fully-unrolled h/x subloops; LDS kq-reduce; fused epilogue.

typedef _Float16 half8 __attribute__((ext_vector_type(8)));
typedef _Float16 half4 __attribute__((ext_vector_type(4)));
typedef float f32x4 __attribute__((ext_vector_type(4)));

#define HSZ 1024
#define BSZ 256
#define TSZ 128

// ---------------- prep: vraw = W^T u (two-stage deterministic) ----------------
__global__ __launch_bounds__(256) void prep_vraw1(
    const float* __restrict__ Wih, const float* __restrict__ Whh,
    const float* __restrict__ uih, const float* __restrict__ uhh,
    float* __restrict__ vpart) {
  int bx = blockIdx.x;                 // 256 blocks: m(4) x rc(16) x jc(4)
  int m = bx >> 6, rc = (bx >> 2) & 15, jc = bx & 3;
  int j = jc * 256 + threadIdx.x;
  const float* W = (m < 2 ? Wih : Whh) + ((size_t)(m & 1) << 22);
  const float* u = (m < 2 ? uih : uhh) + (m & 1) * 4096;
  float acc = 0.f;
  int rbase = rc * 256;
  for (int r = 0; r < 256; ++r)
    acc += W[(size_t)(rbase + r) * 1024 + j] * u[rbase + r];
  vpart[(m * 16 + rc) * 1024 + j] = acc;
}

__global__ __launch_bounds__(256) void prep_vraw2(
    const float* __restrict__ vpart, float* __restrict__ vraw) {
  int i = blockIdx.x * 256 + threadIdx.x;   // 0..4095 -> m*1024+j
  int m = i >> 10;
  float acc = 0.f;
  for (int rc = 0; rc < 16; ++rc)
    acc += vpart[(m * 16 + rc) * 1024 + (i & 1023)];
  vraw[i] = acc;
}

// ---------------- prep: wv = W @ vraw ----------------
__global__ __launch_bounds__(256) void prep_wv(
    const float* __restrict__ Wih, const float* __restrict__ Whh,
    const float* __restrict__ vraw, float* __restrict__ wv) {
  int m = blockIdx.y;
  int w = threadIdx.x >> 6, l = threadIdx.x & 63;
  int r = blockIdx.x * 4 + w;
  const float* W = (m < 2 ? Wih : Whh) + ((size_t)(m & 1) << 22) + (size_t)r * 1024;
  const float* v = vraw + m * 1024;
  float acc = 0.f;
  for (int it = 0; it < 4; ++it) {
    int j = it * 256 + l * 4;
    float4 w4 = *(const float4*)(W + j);
    float4 v4 = *(const float4*)(v + j);
    acc += w4.x * v4.x + w4.y * v4.y + w4.z * v4.z + w4.w * v4.w;
  }
  for (int o = 32; o; o >>= 1) acc += __shfl_down(acc, o);
  if (l == 0) wv[m * 4096 + r] = acc;
}

// ---------------- prep: inv_sigma = ||vraw|| / ||wv|| ----------------
__global__ __launch_bounds__(256) void prep_sig(
    const float* __restrict__ vraw, const float* __restrict__ wv,
    float* __restrict__ invsig) {
  int m = blockIdx.x, tid = threadIdx.x;
  __shared__ float red[256];
  float sv = 0.f, sw = 0.f;
  for (int i = tid; i < 1024; i += 256) { float x = vraw[m * 1024 + i]; sv += x * x; }
  for (int i = tid; i < 4096; i += 256) { float x = wv[m * 4096 + i]; sw += x * x; }
  red[tid] = sv; __syncthreads();
  for (int s = 128; s; s >>= 1) { if (tid < s) red[tid] += red[tid + s]; __syncthreads(); }
  float svt = red[0]; __syncthreads();
  red[tid] = sw; __syncthreads();
  for (int s = 128; s; s >>= 1) { if (tid < s) red[tid] += red[tid + s]; __syncthreads(); }
  if (tid == 0) invsig[m] = sqrtf(svt / red[0]);
}

// ---------------- prep: fragment-packed A (f16, scaled) ----------------
// granule id = ((((layer*64+jc)*8 + w)*32 + (m_local*16+s))*64 + lane), 16 B.
// wave w: kq = w&3 (K-quarter), mh = w>>2 (gate-half). gate = mh*2+m_local.
// k(s) = s<8 ? 1024 + kq*256 + s*32 : kq*256 + (s-8)*32  (+ (lane>>4)*8).
// row = gate*1024 + jc*16 + (lane&15).
__global__ __launch_bounds__(256) void prep_apack(
    const float* __restrict__ Wih, const float* __restrict__ Whh,
    const float* __restrict__ invsig, _Float16* __restrict__ apack) {
  unsigned id = blockIdx.x * 256 + threadIdx.x;   // 0 .. 2^21-1
  int lane = id & 63, f = (id >> 6) & 31, w = (id >> 11) & 7;
  int jc = (id >> 14) & 63, layer = (id >> 20) & 1;
  int kq = w & 3, mh = w >> 2;
  int m_local = f >> 4, s = f & 15;
  int gate = mh * 2 + m_local;
  int lr = lane & 15, lk = lane >> 4;
  int row = gate * 1024 + jc * 16 + lr;
  int k = (s < 8) ? (1024 + kq * 256 + s * 32 + lk * 8)
                  : (kq * 256 + (s - 8) * 32 + lk * 8);
  const float* src; float sc;
  if (k < 1024) {
    src = Wih + ((size_t)layer << 22) + (size_t)row * 1024 + k;
    sc = invsig[layer];
  } else {
    src = Whh + ((size_t)layer << 22) + (size_t)row * 1024 + (k - 1024);
    sc = invsig[2 + layer];
  }
  float4 v0 = *(const float4*)src;
  float4 v1 = *(const float4*)(src + 4);
  half8 o = { (_Float16)(v0.x * sc), (_Float16)(v0.y * sc),
              (_Float16)(v0.z * sc), (_Float16)(v0.w * sc),
              (_Float16)(v1.x * sc), (_Float16)(v1.y * sc),
              (_Float16)(v1.z * sc), (_Float16)(v1.w * sc) };
  *(half8*)(apack + (size_t)id * 8) = o;
}

__global__ __launch_bounds__(256) void prep_bias(
    const float* __restrict__ b_ih, const float* __restrict__ b_hh,
    float* __restrict__ bias) {
  int i = blockIdx.x * 256 + threadIdx.x;
  if (i < 8192) bias[i] = b_ih[i] + b_hh[i];
}

__global__ __launch_bounds__(256) void prep_init(
    const float* __restrict__ x0, const float* __restrict__ h0,
    const float* __restrict__ c0, _Float16* __restrict__ Xinit,
    _Float16* __restrict__ H0p0, _Float16* __restrict__ H1p0,
    float* __restrict__ C0, float* __restrict__ C1) {
  int i = blockIdx.x * 256 + threadIdx.x;   // 0..262143
  Xinit[i] = (_Float16)x0[i];
  H0p0[i]  = (_Float16)h0[i];
  H1p0[i]  = (_Float16)h0[262144 + i];
  C0[i] = c0[i];
  C1[i] = c0[262144 + i];
}

// ---------------- stamp gate: per-jc stamps, ballot poll ----------------
static __device__ __forceinline__ void wait_ge(const unsigned* a, int lane, int tgt) {
  unsigned v = __hip_atomic_load(a + lane, __ATOMIC_RELAXED, __HIP_MEMORY_SCOPE_AGENT);
  while (__any(v < (unsigned)tgt)) {
    __builtin_amdgcn_s_sleep(2);
    v = __hip_atomic_load(a + lane, __ATOMIC_RELAXED, __HIP_MEMORY_SCOPE_AGENT);
  }
  __builtin_amdgcn_fence(__ATOMIC_ACQUIRE, "agent");   // invalidate stale caches
}

// ---------------- the persistent cohort kernel ----------------
__global__ __launch_bounds__(512)
__attribute__((amdgpu_waves_per_eu(2, 2)))       // clamp target occupancy:
void lstm_cohort8(                               // 2 waves/EU -> 256-VGPR budget
    const _Float16* __restrict__ Apack, const float* __restrict__ bias,
    const _Float16* __restrict__ Xinit,
    _Float16* __restrict__ H00, _Float16* __restrict__ H01,
    _Float16* __restrict__ H10, _Float16* __restrict__ H11,
    float* __restrict__ C0, float* __restrict__ C1,
    float* __restrict__ out, unsigned* __restrict__ arr) {
  // [5] not [4]: pushes LDS to 84.5KB so the LDS-derived max occupancy is
  // 1 block/CU (grid is 1/CU anyway) — removes the 4-waves/EU register target
  // that spilled R7/R8. Slice 4 is never touched.
  __shared__ float part[5][64][66];   // [kq][gate-row][batch col +pad]
  const int tid = threadIdx.x, lane = tid & 63, w = tid >> 6;
  const int lr = lane & 15, lk = lane >> 4;
  const int kq = w & 3, mh = w >> 2;
  const int bx = blockIdx.x;
  const int layer = bx & 1, bh = (bx >> 1) & 1, jc = bx >> 2;
  const int j0 = jc * 16, bm0 = bh * 128;

  // ---- A prologue: this wave's K-slice, 128 VGPRs, resident for the run
  half8 a[2][16];
  {
    const _Float16* ab = Apack +
        ((size_t)(((layer * 64 + jc) * 8 + w) * 32) * 64 + lane) * 8;
#pragma unroll
    for (int m = 0; m < 2; ++m)
#pragma unroll
      for (int s = 0; s < 16; ++s)
        a[m][s] = *(const half8*)(ab + (size_t)(m * 16 + s) * 512);
  }

  float* cb = layer ? C1 : C0;
  const float* bs = bias + layer * 4096;
  unsigned* own = arr + (layer * 2 + bh) * 64;
  unsigned* oth = arr + ((1 - layer) * 2 + bh) * 64;

  // epilogue bias preload: thread covers h-cols {rr, rr+8}, rr = tid>>6
  const int rr = tid >> 6, bcol = tid & 63;
  float breg[4][2];
#pragma unroll
  for (int g = 0; g < 4; ++g) {
    breg[g][0] = bs[g * 1024 + j0 + rr];
    breg[g][1] = bs[g * 1024 + j0 + rr + 8];
  }

#pragma unroll 1
  for (int t = 0; t < TSZ; ++t) {
    const int p = t & 1;
    const _Float16* hb = layer ? (p ? H11 : H10) : (p ? H01 : H00);
    const _Float16* xb = layer ? (p ? H00 : H01)
                               : (t == 0 ? Xinit : (p ? H11 : H10));
    _Float16* hw = layer ? (p ? H10 : H11) : (p ? H00 : H01);

    // h-gate: own cohort finished cell t-1
    if (t) wait_ge(own, lane, t);

#define LH(S, BUF) do { _Pragma("unroll")                                     \
    for (int n = 0; n < 4; ++n)                                               \
      bb[BUF][n] = *(const half8*)(hb + ro[n] + kq * 256 + (S) * 32);         \
  } while (0)
#define LX(S, BUF) do { _Pragma("unroll")                                     \
    for (int n = 0; n < 4; ++n)                                               \
      bb[BUF][n] = *(const half8*)(xb + ro[n] + kq * 256 + ((S) - 8) * 32);   \
  } while (0)
#define MF(S, BUF) do { _Pragma("unroll")                                     \
    for (int m = 0; m < 2; ++m) { _Pragma("unroll")                           \
      for (int n = 0; n < 4; ++n)                                             \
        acc[m][n] = __builtin_amdgcn_mfma_f32_16x16x32_f16(                   \
            a[m][S], bb[BUF][n], acc[m][n], 0, 0, 0); }                       \
  } while (0)

#define PASS(NH, GATED) do {                                                  \
    unsigned ro[4];                                                           \
    _Pragma("unroll")                                                         \
    for (int n = 0; n < 4; ++n)                                               \
      ro[n] = (unsigned)(bm0 + (NH) * 64 + n * 16 + lr) * 1024 + lk * 8;      \
    f32x4 acc[2][4];                                                          \
    _Pragma("unroll")                                                         \
    for (int m = 0; m < 2; ++m) { _Pragma("unroll")                           \
      for (int n = 0; n < 4; ++n) acc[m][n] = (f32x4){0.f, 0.f, 0.f, 0.f}; }  \
    half8 bb[2][4];                                                           \
    /* h-subloop: K-tiles 0..7 (state from t-1, covered by h-gate) */         \
    LH(0, 0); LH(1, 1);                                                       \
    MF(0, 0); LH(2, 0);                                                       \
    MF(1, 1); LH(3, 1);                                                       \
    MF(2, 0); LH(4, 0);                                                       \
    MF(3, 1); LH(5, 1);                                                       \
    MF(4, 0); LH(6, 0);                                                       \
    MF(5, 1); LH(7, 1);                                                       \
    MF(6, 0); MF(7, 1);                                                       \
    /* x-gate (outside any unrolled loop; only pass 0 needs it) */            \
    if ((GATED) && !(layer == 0 && t == 0)) wait_ge(oth, lane, t + layer);    \
    /* x-subloop: K-tiles 8..15 */                                            \
    LX(8, 0); LX(9, 1);                                                       \
    MF(8, 0); LX(10, 0);                                                      \
    MF(9, 1); LX(11, 1);                                                      \
    MF(10, 0); LX(12, 0);                                                     \
    MF(11, 1); LX(13, 1);                                                     \
    MF(12, 0); LX(14, 0);                                                     \
    MF(13, 1); LX(15, 1);                                                     \
    MF(14, 0); MF(15, 1);                                                     \
    /* partials -> LDS (2-way bank aliasing max = free) */                    \
    _Pragma("unroll")                                                         \
    for (int m = 0; m < 2; ++m) { _Pragma("unroll")                           \
      for (int n = 0; n < 4; ++n) { _Pragma("unroll")                         \
        for (int j = 0; j < 4; ++j)                                           \
          part[kq][mh * 32 + m * 16 + lk * 4 + j][n * 16 + lr] =              \
              acc[m][n][j]; } }                                               \
    __syncthreads();                                                          \
    /* reduce 4 kq partials + fused LSTM epilogue (2 outputs/thread) */       \
    _Pragma("unroll")                                                         \
    for (int ri = 0; ri < 2; ++ri) {                                          \
      const int rv = rr + 8 * ri;                                             \
      float gi = part[0][rv][bcol] + part[1][rv][bcol] +                      \
                 part[2][rv][bcol] + part[3][rv][bcol] + breg[0][ri];         \
      float gf = part[0][16 + rv][bcol] + part[1][16 + rv][bcol] +            \
                 part[2][16 + rv][bcol] + part[3][16 + rv][bcol] + breg[1][ri];\
      float gg = part[0][32 + rv][bcol] + part[1][32 + rv][bcol] +            \
                 part[2][32 + rv][bcol] + part[3][32 + rv][bcol] + breg[2][ri];\
      float go = part[0][48 + rv][bcol] + part[1][48 + rv][bcol] +            \
                 part[2][48 + rv][bcol] + part[3][48 + rv][bcol] + breg[3][ri];\
      const size_t idx = (size_t)(bm0 + (NH) * 64 + bcol) * 1024 + j0 + rv;   \
      float si = 1.f / (1.f + __expf(-gi));                                   \
      float sf = 1.f / (1.f + __expf(-gf));                                   \
      float so = 1.f / (1.f + __expf(-go));                                   \
      float e2g = __expf(fminf(fmaxf(2.f * gg, -30.f), 30.f));                \
      float tg = (e2g - 1.f) / (e2g + 1.f);                                   \
      float cv = sf * cb[idx] + si * tg;                                      \
      float e2c = __expf(fminf(fmaxf(2.f * cv, -30.f), 30.f));                \
      float tc = (e2c - 1.f) / (e2c + 1.f);                                   \
      cb[idx] = cv;                                                           \
      float hn = so * tc;                                                     \
      hw[idx] = (_Float16)hn;                                                 \
      if (layer)                                                              \
        out[(size_t)(bm0 + (NH) * 64 + bcol) * (TSZ * HSZ) + (size_t)t * HSZ  \
            + j0 + rv] = hn;                                                  \
    }                                                                         \
    __syncthreads();                                                          \
  } while (0)

    PASS(0, 1);
    PASS(1, 0);

#undef LH
#undef LX
#undef MF
#undef PASS

    // publish: __syncthreads drained every wave's stores to L2; release
    // store (wbl2) makes them agent-visible.
    if (tid == 0)
      __hip_atomic_store(own + jc, (unsigned)(t + 1),
                         __ATOMIC_RELEASE, __HIP_MEMORY_SCOPE_AGENT);
  }
}

extern "C" void kernel_launch(void* const* d_in, const int* in_sizes, int n_in,
                              void* d_out, int out_size, void* d_ws, size_t ws_size,
                              hipStream_t stream) {
  (void)in_sizes; (void)n_in; (void)out_size; (void)ws_size;
  const float* x0   = (const float*)d_in[0];
  const float* h0   = (const float*)d_in[1];
  const float* c0   = (const float*)d_in[2];
  const float* Wih  = (const float*)d_in[3];
  const float* Whh  = (const float*)d_in[4];
  const float* b_ih = (const float*)d_in[5];
  const float* b_hh = (const float*)d_in[6];
  const float* u_ih = (const float*)d_in[7];
  const float* u_hh = (const float*)d_in[8];
  float* out = (float*)d_out;

  char* ws = (char*)d_ws;
  size_t off = 0;
  auto alloc = [&](size_t bytes) -> void* {
    void* p = ws + off;
    off = (off + bytes + 255) & ~(size_t)255;
    return p;
  };
  _Float16* apack  = (_Float16*)alloc((size_t)2 * 4096 * 2048 * 2);
  float*    vpart  = (float*)alloc((size_t)4 * 16 * 1024 * 4);
  float*    vraw   = (float*)alloc((size_t)4 * 1024 * 4);
  float*    wv     = (float*)alloc((size_t)4 * 4096 * 4);
  float*    invsig = (float*)alloc(16);
  float*    bias   = (float*)alloc((size_t)2 * 4096 * 4);
  _Float16* Xinit  = (_Float16*)alloc((size_t)262144 * 2);
  _Float16* Hb[2][2];
  for (int a = 0; a < 2; ++a)
    for (int p = 0; p < 2; ++p)
      Hb[a][p] = (_Float16*)alloc((size_t)262144 * 2);
  float* Cb[2];
  Cb[0] = (float*)alloc((size_t)262144 * 4);
  Cb[1] = (float*)alloc((size_t)262144 * 4);
  unsigned* arr = (unsigned*)alloc(4 * 64 * sizeof(unsigned));

  prep_vraw1<<<256, 256, 0, stream>>>(Wih, Whh, u_ih, u_hh, vpart);
  prep_vraw2<<<16, 256, 0, stream>>>(vpart, vraw);
  prep_wv<<<dim3(1024, 4), 256, 0, stream>>>(Wih, Whh, vraw, wv);
  prep_sig<<<4, 256, 0, stream>>>(vraw, wv, invsig);
  prep_apack<<<8192, 256, 0, stream>>>(Wih, Whh, invsig, apack);
  prep_bias<<<32, 256, 0, stream>>>(b_ih, b_hh, bias);
  prep_init<<<1024, 256, 0, stream>>>(x0, h0, c0, Xinit, Hb[0][0], Hb[1][0], Cb[0], Cb[1]);
  hipMemsetAsync(arr, 0, 4 * 64 * sizeof(unsigned), stream);

  lstm_cohort8<<<dim3(256), dim3(512), 0, stream>>>(
      apack, bias, Xinit, Hb[0][0], Hb[0][1], Hb[1][0], Hb[1][1],
      Cb[0], Cb[1], out, arr);
}

// Round 10
// 11768.315 us; speedup vs baseline: 1.3654x; 1.3570x over previous
//
#include <hip/hip_runtime.h>
#include <hip/hip_bf16.h>

// LSTM decoder: B=256, H=1024, L=2, T=128.
// R10: R9 cohort kernel with the GATE STORM fixed. Evidence: R7-R9 FETCH
// (0.7 GB total) rules out scratch-reload of the A-array (would be ~30 TB);
// VGPR_Count=128 is arch-VGPRs only (A/acc live in AGPRs, legal on gfx950).
// The 63 us/phase stall was the gate: 2048 waves x 64 lanes of agent-scope
// atomic polls + per-wave acquire fences hammering 256 B of stamps. Fix:
// ONE wave per block polls (coalesced relaxed loads, s_sleep(8)), one
// acquire fence (L1/L2 inv is per-CU/XCD - covers the block), others wait
// at __syncthreads. Publisher stays a parallel per-jc release store.
// Everything else identical to R9.

typedef _Float16 half8 __attribute__((ext_vector_type(8)));
typedef _Float16 half4 __attribute__((ext_vector_type(4)));
typedef float f32x4 __attribute__((ext_vector_type(4)));

#define HSZ 1024
#define BSZ 256
#define TSZ 128

// ---------------- prep: vraw = W^T u (two-stage deterministic) ----------------
__global__ __launch_bounds__(256) void prep_vraw1(
    const float* __restrict__ Wih, const float* __restrict__ Whh,
    const float* __restrict__ uih, const float* __restrict__ uhh,
    float* __restrict__ vpart) {
  int bx = blockIdx.x;                 // 256 blocks: m(4) x rc(16) x jc(4)
  int m = bx >> 6, rc = (bx >> 2) & 15, jc = bx & 3;
  int j = jc * 256 + threadIdx.x;
  const float* W = (m < 2 ? Wih : Whh) + ((size_t)(m & 1) << 22);
  const float* u = (m < 2 ? uih : uhh) + (m & 1) * 4096;
  float acc = 0.f;
  int rbase = rc * 256;
  for (int r = 0; r < 256; ++r)
    acc += W[(size_t)(rbase + r) * 1024 + j] * u[rbase + r];
  vpart[(m * 16 + rc) * 1024 + j] = acc;
}

__global__ __launch_bounds__(256) void prep_vraw2(
    const float* __restrict__ vpart, float* __restrict__ vraw) {
  int i = blockIdx.x * 256 + threadIdx.x;   // 0..4095 -> m*1024+j
  int m = i >> 10;
  float acc = 0.f;
  for (int rc = 0; rc < 16; ++rc)
    acc += vpart[(m * 16 + rc) * 1024 + (i & 1023)];
  vraw[i] = acc;
}

// ---------------- prep: wv = W @ vraw ----------------
__global__ __launch_bounds__(256) void prep_wv(
    const float* __restrict__ Wih, const float* __restrict__ Whh,
    const float* __restrict__ vraw, float* __restrict__ wv) {
  int m = blockIdx.y;
  int w = threadIdx.x >> 6, l = threadIdx.x & 63;
  int r = blockIdx.x * 4 + w;
  const float* W = (m < 2 ? Wih : Whh) + ((size_t)(m & 1) << 22) + (size_t)r * 1024;
  const float* v = vraw + m * 1024;
  float acc = 0.f;
  for (int it = 0; it < 4; ++it) {
    int j = it * 256 + l * 4;
    float4 w4 = *(const float4*)(W + j);
    float4 v4 = *(const float4*)(v + j);
    acc += w4.x * v4.x + w4.y * v4.y + w4.z * v4.z + w4.w * v4.w;
  }
  for (int o = 32; o; o >>= 1) acc += __shfl_down(acc, o);
  if (l == 0) wv[m * 4096 + r] = acc;
}

// ---------------- prep: inv_sigma = ||vraw|| / ||wv|| ----------------
__global__ __launch_bounds__(256) void prep_sig(
    const float* __restrict__ vraw, const float* __restrict__ wv,
    float* __restrict__ invsig) {
  int m = blockIdx.x, tid = threadIdx.x;
  __shared__ float red[256];
  float sv = 0.f, sw = 0.f;
  for (int i = tid; i < 1024; i += 256) { float x = vraw[m * 1024 + i]; sv += x * x; }
  for (int i = tid; i < 4096; i += 256) { float x = wv[m * 4096 + i]; sw += x * x; }
  red[tid] = sv; __syncthreads();
  for (int s = 128; s; s >>= 1) { if (tid < s) red[tid] += red[tid + s]; __syncthreads(); }
  float svt = red[0]; __syncthreads();
  red[tid] = sw; __syncthreads();
  for (int s = 128; s; s >>= 1) { if (tid < s) red[tid] += red[tid + s]; __syncthreads(); }
  if (tid == 0) invsig[m] = sqrtf(svt / red[0]);
}

// ---------------- prep: fragment-packed A (f16, scaled) ----------------
// granule id = ((((layer*64+jc)*8 + w)*32 + (m_local*16+s))*64 + lane), 16 B.
// wave w: kq = w&3 (K-quarter), mh = w>>2 (gate-half). gate = mh*2+m_local.
// k(s) = s<8 ? 1024 + kq*256 + s*32 : kq*256 + (s-8)*32  (+ (lane>>4)*8).
// row = gate*1024 + jc*16 + (lane&15).
__global__ __launch_bounds__(256) void prep_apack(
    const float* __restrict__ Wih, const float* __restrict__ Whh,
    const float* __restrict__ invsig, _Float16* __restrict__ apack) {
  unsigned id = blockIdx.x * 256 + threadIdx.x;   // 0 .. 2^21-1
  int lane = id & 63, f = (id >> 6) & 31, w = (id >> 11) & 7;
  int jc = (id >> 14) & 63, layer = (id >> 20) & 1;
  int kq = w & 3, mh = w >> 2;
  int m_local = f >> 4, s = f & 15;
  int gate = mh * 2 + m_local;
  int lr = lane & 15, lk = lane >> 4;
  int row = gate * 1024 + jc * 16 + lr;
  int k = (s < 8) ? (1024 + kq * 256 + s * 32 + lk * 8)
                  : (kq * 256 + (s - 8) * 32 + lk * 8);
  const float* src; float sc;
  if (k < 1024) {
    src = Wih + ((size_t)layer << 22) + (size_t)row * 1024 + k;
    sc = invsig[layer];
  } else {
    src = Whh + ((size_t)layer << 22) + (size_t)row * 1024 + (k - 1024);
    sc = invsig[2 + layer];
  }
  float4 v0 = *(const float4*)src;
  float4 v1 = *(const float4*)(src + 4);
  half8 o = { (_Float16)(v0.x * sc), (_Float16)(v0.y * sc),
              (_Float16)(v0.z * sc), (_Float16)(v0.w * sc),
              (_Float16)(v1.x * sc), (_Float16)(v1.y * sc),
              (_Float16)(v1.z * sc), (_Float16)(v1.w * sc) };
  *(half8*)(apack + (size_t)id * 8) = o;
}

__global__ __launch_bounds__(256) void prep_bias(
    const float* __restrict__ b_ih, const float* __restrict__ b_hh,
    float* __restrict__ bias) {
  int i = blockIdx.x * 256 + threadIdx.x;
  if (i < 8192) bias[i] = b_ih[i] + b_hh[i];
}

__global__ __launch_bounds__(256) void prep_init(
    const float* __restrict__ x0, const float* __restrict__ h0,
    const float* __restrict__ c0, _Float16* __restrict__ Xinit,
    _Float16* __restrict__ H0p0, _Float16* __restrict__ H1p0,
    float* __restrict__ C0, float* __restrict__ C1) {
  int i = blockIdx.x * 256 + threadIdx.x;   // 0..262143
  Xinit[i] = (_Float16)x0[i];
  H0p0[i]  = (_Float16)h0[i];
  H1p0[i]  = (_Float16)h0[262144 + i];
  C0[i] = c0[i];
  C1[i] = c0[262144 + i];
}

// ---------------- stamp gate: per-jc stamps, single-wave ballot poll ----------
static __device__ __forceinline__ void wait_ge(const unsigned* a, int lane, int tgt) {
  unsigned v = __hip_atomic_load(a + lane, __ATOMIC_RELAXED, __HIP_MEMORY_SCOPE_AGENT);
  while (__any(v < (unsigned)tgt)) {
    __builtin_amdgcn_s_sleep(8);
    v = __hip_atomic_load(a + lane, __ATOMIC_RELAXED, __HIP_MEMORY_SCOPE_AGENT);
  }
  __builtin_amdgcn_fence(__ATOMIC_ACQUIRE, "agent");   // invalidate stale caches
}

// ---------------- the persistent cohort kernel ----------------
__global__ __launch_bounds__(512)
__attribute__((amdgpu_waves_per_eu(2, 2)))
void lstm_cohort8(
    const _Float16* __restrict__ Apack, const float* __restrict__ bias,
    const _Float16* __restrict__ Xinit,
    _Float16* __restrict__ H00, _Float16* __restrict__ H01,
    _Float16* __restrict__ H10, _Float16* __restrict__ H11,
    float* __restrict__ C0, float* __restrict__ C1,
    float* __restrict__ out, unsigned* __restrict__ arr) {
  // [5] keeps LDS at 84.5KB -> 1 block/CU (grid is 1/CU anyway).
  __shared__ float part[5][64][66];   // [kq][gate-row][batch col +pad]
  const int tid = threadIdx.x, lane = tid & 63, w = tid >> 6;
  const int lr = lane & 15, lk = lane >> 4;
  const int kq = w & 3, mh = w >> 2;
  const int bx = blockIdx.x;
  const int layer = bx & 1, bh = (bx >> 1) & 1, jc = bx >> 2;
  const int j0 = jc * 16, bm0 = bh * 128;

  // ---- A prologue: this wave's K-slice, resident for the run
  half8 a[2][16];
  {
    const _Float16* ab = Apack +
        ((size_t)(((layer * 64 + jc) * 8 + w) * 32) * 64 + lane) * 8;
#pragma unroll
    for (int m = 0; m < 2; ++m)
#pragma unroll
      for (int s = 0; s < 16; ++s)
        a[m][s] = *(const half8*)(ab + (size_t)(m * 16 + s) * 512);
  }

  float* cb = layer ? C1 : C0;
  const float* bs = bias + layer * 4096;
  unsigned* own = arr + (layer * 2 + bh) * 64;
  unsigned* oth = arr + ((1 - layer) * 2 + bh) * 64;

  // epilogue bias preload: thread covers h-cols {rr, rr+8}, rr = tid>>6
  const int rr = tid >> 6, bcol = tid & 63;
  float breg[4][2];
#pragma unroll
  for (int g = 0; g < 4; ++g) {
    breg[g][0] = bs[g * 1024 + j0 + rr];
    breg[g][1] = bs[g * 1024 + j0 + rr + 8];
  }

#pragma unroll 1
  for (int t = 0; t < TSZ; ++t) {
    const int p = t & 1;
    const _Float16* hb = layer ? (p ? H11 : H10) : (p ? H01 : H00);
    const _Float16* xb = layer ? (p ? H00 : H01)
                               : (t == 0 ? Xinit : (p ? H11 : H10));
    _Float16* hw = layer ? (p ? H10 : H11) : (p ? H00 : H01);

    // h-gate: own cohort finished cell t-1. ONLY WAVE 0 POLLS (gate-storm
    // fix); its acquire fence invalidates the CU/XCD caches for the whole
    // block; everyone else waits at the barrier.
    if (t) {
      if (w == 0) wait_ge(own, lane, t);
      __syncthreads();
    }

#define LH(S, BUF) do { _Pragma("unroll")                                     \
    for (int n = 0; n < 4; ++n)                                               \
      bb[BUF][n] = *(const half8*)(hb + ro[n] + kq * 256 + (S) * 32);         \
  } while (0)
#define LX(S, BUF) do { _Pragma("unroll")                                     \
    for (int n = 0; n < 4; ++n)                                               \
      bb[BUF][n] = *(const half8*)(xb + ro[n] + kq * 256 + ((S) - 8) * 32);   \
  } while (0)
#define MF(S, BUF) do { _Pragma("unroll")                                     \
    for (int m = 0; m < 2; ++m) { _Pragma("unroll")                           \
      for (int n = 0; n < 4; ++n)                                             \
        acc[m][n] = __builtin_amdgcn_mfma_f32_16x16x32_f16(                   \
            a[m][S], bb[BUF][n], acc[m][n], 0, 0, 0); }                       \
  } while (0)

#define PASS(NH, GATED) do {                                                  \
    unsigned ro[4];                                                           \
    _Pragma("unroll")                                                         \
    for (int n = 0; n < 4; ++n)                                               \
      ro[n] = (unsigned)(bm0 + (NH) * 64 + n * 16 + lr) * 1024 + lk * 8;      \
    f32x4 acc[2][4];                                                          \
    _Pragma("unroll")                                                         \
    for (int m = 0; m < 2; ++m) { _Pragma("unroll")                           \
      for (int n = 0; n < 4; ++n) acc[m][n] = (f32x4){0.f, 0.f, 0.f, 0.f}; }  \
    half8 bb[2][4];                                                           \
    /* h-subloop: K-tiles 0..7 (state from t-1, covered by h-gate) */         \
    LH(0, 0); LH(1, 1);                                                       \
    MF(0, 0); LH(2, 0);                                                       \
    MF(1, 1); LH(3, 1);                                                       \
    MF(2, 0); LH(4, 0);                                                       \
    MF(3, 1); LH(5, 1);                                                       \
    MF(4, 0); LH(6, 0);                                                       \
    MF(5, 1); LH(7, 1);                                                       \
    MF(6, 0); MF(7, 1);                                                       \
    /* x-gate: single-wave poll + block barrier (gate-storm fix) */           \
    if ((GATED) && !(layer == 0 && t == 0)) {                                 \
      if (w == 0) wait_ge(oth, lane, t + layer);                              \
      __syncthreads();                                                        \
    }                                                                         \
    /* x-subloop: K-tiles 8..15 */                                            \
    LX(8, 0); LX(9, 1);                                                       \
    MF(8, 0); LX(10, 0);                                                      \
    MF(9, 1); LX(11, 1);                                                      \
    MF(10, 0); LX(12, 0);                                                     \
    MF(11, 1); LX(13, 1);                                                     \
    MF(12, 0); LX(14, 0);                                                     \
    MF(13, 1); LX(15, 1);                                                     \
    MF(14, 0); MF(15, 1);                                                     \
    /* partials -> LDS (2-way bank aliasing max = free) */                    \
    _Pragma("unroll")                                                         \
    for (int m = 0; m < 2; ++m) { _Pragma("unroll")                           \
      for (int n = 0; n < 4; ++n) { _Pragma("unroll")                         \
        for (int j = 0; j < 4; ++j)                                           \
          part[kq][mh * 32 + m * 16 + lk * 4 + j][n * 16 + lr] =              \
              acc[m][n][j]; } }                                               \
    __syncthreads();                                                          \
    /* reduce 4 kq partials + fused LSTM epilogue (2 outputs/thread) */       \
    _Pragma("unroll")                                                         \
    for (int ri = 0; ri < 2; ++ri) {                                          \
      const int rv = rr + 8 * ri;                                             \
      float gi = part[0][rv][bcol] + part[1][rv][bcol] +                      \
                 part[2][rv][bcol] + part[3][rv][bcol] + breg[0][ri];         \
      float gf = part[0][16 + rv][bcol] + part[1][16 + rv][bcol] +            \
                 part[2][16 + rv][bcol] + part[3][16 + rv][bcol] + breg[1][ri];\
      float gg = part[0][32 + rv][bcol] + part[1][32 + rv][bcol] +            \
                 part[2][32 + rv][bcol] + part[3][32 + rv][bcol] + breg[2][ri];\
      float go = part[0][48 + rv][bcol] + part[1][48 + rv][bcol] +            \
                 part[2][48 + rv][bcol] + part[3][48 + rv][bcol] + breg[3][ri];\
      const size_t idx = (size_t)(bm0 + (NH) * 64 + bcol) * 1024 + j0 + rv;   \
      float si = 1.f / (1.f + __expf(-gi));                                   \
      float sf = 1.f / (1.f + __expf(-gf));                                   \
      float so = 1.f / (1.f + __expf(-go));                                   \
      float e2g = __expf(fminf(fmaxf(2.f * gg, -30.f), 30.f));                \
      float tg = (e2g - 1.f) / (e2g + 1.f);                                   \
      float cv = sf * cb[idx] + si * tg;                                      \
      float e2c = __expf(fminf(fmaxf(2.f * cv, -30.f), 30.f));                \
      float tc = (e2c - 1.f) / (e2c + 1.f);                                   \
      cb[idx] = cv;                                                           \
      float hn = so * tc;                                                     \
      hw[idx] = (_Float16)hn;                                                 \
      if (layer)                                                              \
        out[(size_t)(bm0 + (NH) * 64 + bcol) * (TSZ * HSZ) + (size_t)t * HSZ  \
            + j0 + rv] = hn;                                                  \
    }                                                                         \
    __syncthreads();                                                          \
  } while (0)

    PASS(0, 1);
    PASS(1, 0);

#undef LH
#undef LX
#undef MF
#undef PASS

    // publish: __syncthreads drained every wave's stores to L2; release
    // store makes them agent-visible. Parallel per-jc store (no RMW).
    if (tid == 0)
      __hip_atomic_store(own + jc, (unsigned)(t + 1),
                         __ATOMIC_RELEASE, __HIP_MEMORY_SCOPE_AGENT);
  }
}

extern "C" void kernel_launch(void* const* d_in, const int* in_sizes, int n_in,
                              void* d_out, int out_size, void* d_ws, size_t ws_size,
                              hipStream_t stream) {
  (void)in_sizes; (void)n_in; (void)out_size; (void)ws_size;
  const float* x0   = (const float*)d_in[0];
  const float* h0   = (const float*)d_in[1];
  const float* c0   = (const float*)d_in[2];
  const float* Wih  = (const float*)d_in[3];
  const float* Whh  = (const float*)d_in[4];
  const float* b_ih = (const float*)d_in[5];
  const float* b_hh = (const float*)d_in[6];
  const float* u_ih = (const float*)d_in[7];
  const float* u_hh = (const float*)d_in[8];
  float* out = (float*)d_out;

  char* ws = (char*)d_ws;
  size_t off = 0;
  auto alloc = [&](size_t bytes) -> void* {
    void* p = ws + off;
    off = (off + bytes + 255) & ~(size_t)255;
    return p;
  };
  _Float16* apack  = (_Float16*)alloc((size_t)2 * 4096 * 2048 * 2);
  float*    vpart  = (float*)alloc((size_t)4 * 16 * 1024 * 4);
  float*    vraw   = (float*)alloc((size_t)4 * 1024 * 4);
  float*    wv     = (float*)alloc((size_t)4 * 4096 * 4);
  float*    invsig = (float*)alloc(16);
  float*    bias   = (float*)alloc((size_t)2 * 4096 * 4);
  _Float16* Xinit  = (_Float16*)alloc((size_t)262144 * 2);
  _Float16* Hb[2][2];
  for (int a = 0; a < 2; ++a)
    for (int p = 0; p < 2; ++p)
      Hb[a][p] = (_Float16*)alloc((size_t)262144 * 2);
  float* Cb[2];
  Cb[0] = (float*)alloc((size_t)262144 * 4);
  Cb[1] = (float*)alloc((size_t)262144 * 4);
  unsigned* arr = (unsigned*)alloc(4 * 64 * sizeof(unsigned));

  prep_vraw1<<<256, 256, 0, stream>>>(Wih, Whh, u_ih, u_hh, vpart);
  prep_vraw2<<<16, 256, 0, stream>>>(vpart, vraw);
  prep_wv<<<dim3(1024, 4), 256, 0, stream>>>(Wih, Whh, vraw, wv);
  prep_sig<<<4, 256, 0, stream>>>(vraw, wv, invsig);
  prep_apack<<<8192, 256, 0, stream>>>(Wih, Whh, invsig, apack);
  prep_bias<<<32, 256, 0, stream>>>(b_ih, b_hh, bias);
  prep_init<<<1024, 256, 0, stream>>>(x0, h0, c0, Xinit, Hb[0][0], Hb[1][0], Cb[0], Cb[1]);
  hipMemsetAsync(arr, 0, 4 * 64 * sizeof(unsigned), stream);

  lstm_cohort8<<<dim3(256), dim3(512), 0, stream>>>(
      apack, bias, Xinit, Hb[0][0], Hb[0][1], Hb[1][0], Hb[1][1],
      Cb[0], Cb[1], out, arr);
}

// Round 11
// 5233.580 us; speedup vs baseline: 3.0703x; 2.2486x over previous
//
#include <hip/hip_runtime.h>
#include <hip/hip_bf16.h>

// LSTM decoder: B=256, H=1024, L=2, T=128.
// R11: combine the two proven halves. GEMM engine = R3/R5's LDS-staged
// counted-vmcnt pipeline (global_load_lds w16, 3x32KB buffers, 64x64 tile,
// BK=128, 4 waves of 32x32) — measured ~4.7-7us/cell. Sync = R10's cheap
// gates (per-block stamp + release store publish; wave-0-only 64-lane
// relaxed poll + one acquire fence per block; raw s_barrier so in-flight
// prefetch survives). One gate per phase (deps are bm-group-local).
// W-staging of tiles 0-1 issues BEFORE the gate (weights immutable ->
// stale-cache safe), hiding A-fetch under the gate; first vmcnt is 12.

typedef _Float16 half8 __attribute__((ext_vector_type(8)));
typedef _Float16 half4 __attribute__((ext_vector_type(4)));
typedef float f32x4 __attribute__((ext_vector_type(4)));

#define HSZ 1024
#define BSZ 256
#define TSZ 128
#define NBLK 256

#define AS1 __attribute__((address_space(1)))
#define AS3 __attribute__((address_space(3)))

static __device__ __forceinline__ void gload16(const void* g, void* l) {
  __builtin_amdgcn_global_load_lds((const AS1 unsigned int*)g,
                                   (AS3 unsigned int*)l, 16, 0, 0);
}

// ---------------- prep: vraw = W^T u (two-stage deterministic) ----------------
__global__ __launch_bounds__(256) void prep_vraw1(
    const float* __restrict__ Wih, const float* __restrict__ Whh,
    const float* __restrict__ uih, const float* __restrict__ uhh,
    float* __restrict__ vpart) {
  int bx = blockIdx.x;                 // 256 blocks: m(4) x rc(16) x jc(4)
  int m = bx >> 6, rc = (bx >> 2) & 15, jc = bx & 3;
  int j = jc * 256 + threadIdx.x;
  const float* W = (m < 2 ? Wih : Whh) + ((size_t)(m & 1) << 22);
  const float* u = (m < 2 ? uih : uhh) + (m & 1) * 4096;
  float acc = 0.f;
  int rbase = rc * 256;
  for (int r = 0; r < 256; ++r)
    acc += W[(size_t)(rbase + r) * 1024 + j] * u[rbase + r];
  vpart[(m * 16 + rc) * 1024 + j] = acc;
}

__global__ __launch_bounds__(256) void prep_vraw2(
    const float* __restrict__ vpart, float* __restrict__ vraw) {
  int i = blockIdx.x * 256 + threadIdx.x;   // 0..4095 -> m*1024+j
  int m = i >> 10;
  float acc = 0.f;
  for (int rc = 0; rc < 16; ++rc)
    acc += vpart[(m * 16 + rc) * 1024 + (i & 1023)];
  vraw[i] = acc;
}

// ---------------- prep: wv = W @ vraw ----------------
__global__ __launch_bounds__(256) void prep_wv(
    const float* __restrict__ Wih, const float* __restrict__ Whh,
    const float* __restrict__ vraw, float* __restrict__ wv) {
  int m = blockIdx.y;
  int w = threadIdx.x >> 6, l = threadIdx.x & 63;
  int r = blockIdx.x * 4 + w;
  const float* W = (m < 2 ? Wih : Whh) + ((size_t)(m & 1) << 22) + (size_t)r * 1024;
  const float* v = vraw + m * 1024;
  float acc = 0.f;
  for (int it = 0; it < 4; ++it) {
    int j = it * 256 + l * 4;
    float4 w4 = *(const float4*)(W + j);
    float4 v4 = *(const float4*)(v + j);
    acc += w4.x * v4.x + w4.y * v4.y + w4.z * v4.z + w4.w * v4.w;
  }
  for (int o = 32; o; o >>= 1) acc += __shfl_down(acc, o);
  if (l == 0) wv[m * 4096 + r] = acc;
}

// ---------------- prep: inv_sigma = ||vraw|| / ||wv|| ----------------
__global__ __launch_bounds__(256) void prep_sig(
    const float* __restrict__ vraw, const float* __restrict__ wv,
    float* __restrict__ invsig) {
  int m = blockIdx.x, tid = threadIdx.x;
  __shared__ float red[256];
  float sv = 0.f, sw = 0.f;
  for (int i = tid; i < 1024; i += 256) { float x = vraw[m * 1024 + i]; sv += x * x; }
  for (int i = tid; i < 4096; i += 256) { float x = wv[m * 4096 + i]; sw += x * x; }
  red[tid] = sv; __syncthreads();
  for (int s = 128; s; s >>= 1) { if (tid < s) red[tid] += red[tid + s]; __syncthreads(); }
  float svt = red[0]; __syncthreads();
  red[tid] = sw; __syncthreads();
  for (int s = 128; s; s >>= 1) { if (tid < s) red[tid] += red[tid + s]; __syncthreads(); }
  if (tid == 0) invsig[m] = sqrtf(svt / red[0]);
}

// ---------------- prep: Wcomb f16 = [Wih | Whh] * inv_sigma ----------------
__global__ __launch_bounds__(256) void prep_wcomb(
    const float* __restrict__ Wih, const float* __restrict__ Whh,
    const float* __restrict__ invsig, _Float16* __restrict__ wcomb) {
  size_t idx4 = ((size_t)blockIdx.x * 256 + threadIdx.x) * 4;
  if (idx4 >= (size_t)2 * 4096 * 2048) return;
  int l = (int)(idx4 >> 23);
  int rem = (int)(idx4 & ((1u << 23) - 1));
  int r = rem >> 11, k = rem & 2047;
  const float* src; float s;
  if (k < 1024) { src = Wih + ((size_t)l << 22) + (size_t)r * 1024 + k; s = invsig[l]; }
  else          { src = Whh + ((size_t)l << 22) + (size_t)r * 1024 + (k - 1024); s = invsig[2 + l]; }
  float4 v = *(const float4*)src;
  half4 o = { (_Float16)(v.x * s), (_Float16)(v.y * s),
              (_Float16)(v.z * s), (_Float16)(v.w * s) };
  *(half4*)(wcomb + idx4) = o;
}

__global__ __launch_bounds__(256) void prep_bias(
    const float* __restrict__ b_ih, const float* __restrict__ b_hh,
    float* __restrict__ bias) {
  int i = blockIdx.x * 256 + threadIdx.x;
  if (i < 8192) bias[i] = b_ih[i] + b_hh[i];
}

__global__ __launch_bounds__(256) void prep_init(
    const float* __restrict__ x0, const float* __restrict__ h0,
    const float* __restrict__ c0, _Float16* __restrict__ Xinit,
    _Float16* __restrict__ H0p0, _Float16* __restrict__ H1p0,
    float* __restrict__ C0, float* __restrict__ C1) {
  int i = blockIdx.x * 256 + threadIdx.x;   // 0..262143
  Xinit[i] = (_Float16)x0[i];
  H0p0[i]  = (_Float16)h0[i];
  H1p0[i]  = (_Float16)h0[262144 + i];
  C0[i] = c0[i];
  C1[i] = c0[262144 + i];
}

// ---------------- stamp gate: single-wave ballot poll ----------------
static __device__ __forceinline__ void wait_ge(const unsigned* a, int lane, int tgt) {
  unsigned v = __hip_atomic_load(a + lane, __ATOMIC_RELAXED, __HIP_MEMORY_SCOPE_AGENT);
  while (__any(v < (unsigned)tgt)) {
    __builtin_amdgcn_s_sleep(4);
    v = __hip_atomic_load(a + lane, __ATOMIC_RELAXED, __HIP_MEMORY_SCOPE_AGENT);
  }
  __builtin_amdgcn_fence(__ATOMIC_ACQUIRE, "agent");   // inv stale L1/L2
}

// ---------------- persistent LSTM kernel ----------------
struct Desc {
  size_t abase[4];   // W row base + swizzled in-slice offset (add bi*256)
  int    brow[4];    // local batch row
  int    bswz[4];    // swizzled in-slice offset for B (add k0b)
  int    dst16[4];   // LDS byte offset of granule within tile
};

// one cell-phase: gates GEMM (counted-vmcnt 3-buffer pipeline) + LSTM epilogue
// gtgt >= 0: wait own-group stamps >= gtgt between A-prefetch and B-staging.
static __device__ __forceinline__ void cell_phase(
    const _Float16* __restrict__ W, const float* __restrict__ bs,
    const _Float16* __restrict__ xbuf, const _Float16* __restrict__ hbuf,
    float* __restrict__ cbuf, _Float16* __restrict__ hout, float* yout,
    char* smem, const Desc& d, int j0, int bm0, int tid,
    const unsigned* gstamp, int gtgt) {
  const int lane = tid & 63, w = tid >> 6;
  const int wr = w & 1, wc = w >> 1;
  const int lr = lane & 15, lk = lane >> 4;
  const char* Wb = (const char*)W;
  const char* Xb = (const char*)xbuf;
  const char* Hc = (const char*)hbuf;

  f32x4 acc00 = {0,0,0,0}, acc01 = {0,0,0,0}, acc10 = {0,0,0,0}, acc11 = {0,0,0,0};
  const int ar0 = wr * 32 + lr, ar1 = ar0 + 16;
  const int br0 = wc * 32 + lr, br1 = br0 + 16;

#define STAGE_A(p, bi) do {                                                   \
    const size_t ka = (size_t)(bi) * 256;                                     \
    char* lb = smem + (p) * 32768;                                            \
    _Pragma("unroll")                                                         \
    for (int q = 0; q < 4; ++q)                                               \
      gload16(Wb + d.abase[q] + ka, lb + d.dst16[q]);                         \
  } while (0)

#define STAGE_B(p, bi) do {                                                   \
    const char* actb = ((bi) < 8) ? Xb : Hc;                                  \
    const size_t k0b = (size_t)((bi) & 7) * 256;                              \
    char* lb = smem + (p) * 32768;                                            \
    _Pragma("unroll")                                                         \
    for (int q = 0; q < 4; ++q)                                               \
      gload16(actb + (size_t)(bm0 + d.brow[q]) * 2048 + k0b + d.bswz[q],      \
              lb + 16384 + d.dst16[q]);                                       \
  } while (0)

#define STAGE(p, bi) do { STAGE_A(p, bi); STAGE_B(p, bi); } while (0)

#define LDSOFF(row, s) ((row) * 256 + (((((s) << 2) + lk) ^ ((row) & 7)) << 4))

#define COMPUTE(p) do {                                                       \
    const _Float16* Ab = (const _Float16*)(smem + (p) * 32768);               \
    const _Float16* Bb = (const _Float16*)(smem + (p) * 32768 + 16384);       \
    _Pragma("unroll")                                                         \
    for (int s = 0; s < 4; ++s) {                                             \
      half8 a0 = *(const half8*)(Ab + (LDSOFF(ar0, s) >> 1));                 \
      half8 a1 = *(const half8*)(Ab + (LDSOFF(ar1, s) >> 1));                 \
      half8 b0 = *(const half8*)(Bb + (LDSOFF(br0, s) >> 1));                 \
      half8 b1 = *(const half8*)(Bb + (LDSOFF(br1, s) >> 1));                 \
      acc00 = __builtin_amdgcn_mfma_f32_16x16x32_f16(a0, b0, acc00, 0, 0, 0); \
      acc01 = __builtin_amdgcn_mfma_f32_16x16x32_f16(a0, b1, acc01, 0, 0, 0); \
      acc10 = __builtin_amdgcn_mfma_f32_16x16x32_f16(a1, b0, acc10, 0, 0, 0); \
      acc11 = __builtin_amdgcn_mfma_f32_16x16x32_f16(a1, b1, acc11, 0, 0, 0); \
    }                                                                         \
  } while (0)

#define WAITVM(N) asm volatile("s_waitcnt vmcnt(" #N ")" ::: "memory")
#define BAR() do { asm volatile("" ::: "memory");                             \
    __builtin_amdgcn_s_barrier();                                             \
    asm volatile("" ::: "memory"); } while (0)

  // A-prefetch for tiles 0,1 BEFORE the gate (weights immutable; stale-cache
  // safe; hides W fetch under the gate wait).
  STAGE_A(0, 0);
  STAGE_A(1, 1);
  if (gtgt >= 0) {
    if (w == 0) wait_ge(gstamp, lane, gtgt);
    BAR();                     // raw barrier: no vmcnt drain, prefetch lives
  }
  STAGE_B(0, 0);
  STAGE_B(1, 1);

  // queue: A0 A1 B0 B1 | T2.. ; first wait retires A0,A1,B0 -> vmcnt(12).
#define ITER(bi, pb, ps) do {                                                 \
    STAGE(ps, (bi) + 2);                                                      \
    WAITVM(16); BAR();                                                        \
    COMPUTE(pb);                                                              \
    BAR(); } while (0)

  STAGE(2, 2); WAITVM(12); BAR(); COMPUTE(0); BAR();
  ITER(1, 1, 0);  ITER(2, 2, 1);  ITER(3, 0, 2);
  ITER(4, 1, 0);  ITER(5, 2, 1);  ITER(6, 0, 2);  ITER(7, 1, 0);
  ITER(8, 2, 1);  ITER(9, 0, 2);  ITER(10, 1, 0); ITER(11, 2, 1);
  ITER(12, 0, 2); ITER(13, 1, 0);
  WAITVM(8);  BAR(); COMPUTE(2); BAR();
  WAITVM(0);  BAR(); COMPUTE(0); BAR();

  // gate exchange through LDS (aliases staging smem — safe after barrier)
  float (*gl)[65] = (float(*)[65])smem;
#pragma unroll
  for (int i = 0; i < 2; ++i) {
    const int rbase = wr * 32 + i * 16 + lk * 4;
    f32x4 v0 = (i == 0) ? acc00 : acc10;
    f32x4 v1 = (i == 0) ? acc01 : acc11;
#pragma unroll
    for (int rr = 0; rr < 4; ++rr) {
      gl[rbase + rr][wc * 32 + lr] = v0[rr];
      gl[rbase + rr][wc * 32 + 16 + lr] = v1[rr];
    }
  }
  __syncthreads();

  // recombine + LSTM elementwise. thread: b = tid>>2, 4 consecutive h-cols.
  {
    const int b = tid >> 2, jj = tid & 3;
    const float* bp = bs + j0 + jj * 4;
    float4 bi4 = *(const float4*)(bp);
    float4 bf4 = *(const float4*)(bp + 1024);
    float4 bg4 = *(const float4*)(bp + 2048);
    float4 bo4 = *(const float4*)(bp + 3072);
    const size_t idx = (size_t)(bm0 + b) * 1024 + j0 + jj * 4;
    float4 c4 = *(const float4*)&cbuf[idx];
    float cn4[4], hn4[4];
    const float* bi_p = &bi4.x; const float* bf_p = &bf4.x;
    const float* bg_p = &bg4.x; const float* bo_p = &bo4.x;
    const float* c_p = &c4.x;
#pragma unroll
    for (int cc = 0; cc < 4; ++cc) {
      const int r = jj * 4 + cc;
      float iv = gl[r][b]      + bi_p[cc];
      float fv = gl[16 + r][b] + bf_p[cc];
      float gv = gl[32 + r][b] + bg_p[cc];
      float ov = gl[48 + r][b] + bo_p[cc];
      float si = 1.f / (1.f + __expf(-iv));
      float sf = 1.f / (1.f + __expf(-fv));
      float so = 1.f / (1.f + __expf(-ov));
      float e2g = __expf(fminf(fmaxf(2.f * gv, -30.f), 30.f));
      float tg = (e2g - 1.f) / (e2g + 1.f);
      float cn = sf * c_p[cc] + si * tg;
      float e2c = __expf(fminf(fmaxf(2.f * cn, -30.f), 30.f));
      float tc = (e2c - 1.f) / (e2c + 1.f);
      cn4[cc] = cn;
      hn4[cc] = so * tc;
    }
    float4 cno = { cn4[0], cn4[1], cn4[2], cn4[3] };
    *(float4*)&cbuf[idx] = cno;
    half4 h4 = { (_Float16)hn4[0], (_Float16)hn4[1],
                 (_Float16)hn4[2], (_Float16)hn4[3] };
    *(half4*)&hout[idx] = h4;
    if (yout) {
      float4 y4 = { hn4[0], hn4[1], hn4[2], hn4[3] };
      *(float4*)&yout[(size_t)(bm0 + b) * (TSZ * HSZ) + j0 + jj * 4] = y4;
    }
  }
  // drain all stores + protect gl/smem before next phase's A-prefetch.
  __syncthreads();
#undef STAGE_A
#undef STAGE_B
#undef STAGE
#undef LDSOFF
#undef COMPUTE
#undef WAITVM
#undef BAR
#undef ITER
}

__global__ __launch_bounds__(256) void lstm_persist(
    const _Float16* __restrict__ W0, const _Float16* __restrict__ W1,
    const float* __restrict__ bias, const _Float16* __restrict__ Xinit,
    _Float16* __restrict__ H00, _Float16* __restrict__ H01,
    _Float16* __restrict__ H10, _Float16* __restrict__ H11,
    float* __restrict__ C0, float* __restrict__ C1,
    float* __restrict__ out, unsigned* __restrict__ arr) {
  __shared__ __align__(16) char smem[98304];   // 3 bufs x (A 16K + B 16K)
  const int tid = threadIdx.x;
  const int bx = blockIdx.x;
  const int jc = bx & 63, grp = bx >> 6;
  const int j0 = jc * 16;
  const int bm0 = grp * 64;

  Desc d;
#pragma unroll
  for (int q = 0; q < 4; ++q) {
    int c = q * 256 + tid;
    int row = c >> 4, g16 = c & 15;
    int srcg = (g16 ^ (row & 7)) << 4;
    int grow = (row >> 4) * 1024 + j0 + (row & 15);
    d.abase[q] = (size_t)grow * 4096 + srcg;
    d.brow[q] = row; d.bswz[q] = srcg;
    d.dst16[q] = c * 16;
  }

  _Float16* H0[2] = { H00, H01 };
  _Float16* H1[2] = { H10, H11 };
  unsigned* own = arr + grp * 64;   // 64 stamps, one per jc in this bm-group

#pragma unroll 1
  for (int ph = 0; ph < 2 * TSZ; ++ph) {
    const int t = ph >> 1, layer = ph & 1, p = t & 1;
    if (layer == 0) {
      cell_phase(W0, bias,
                 (t == 0 ? Xinit : H1[p]), H0[p], C0, H0[p ^ 1], nullptr,
                 smem, d, j0, bm0, tid, own, (ph == 0 ? -1 : ph));
    } else {
      cell_phase(W1, bias + 4096,
                 H0[p ^ 1], H1[p], C1, H1[p ^ 1], out + (size_t)t * HSZ,
                 smem, d, j0, bm0, tid, own, ph);
    }
    // publish: cell_phase's trailing __syncthreads drained all waves' stores;
    // release store writes back L2 making them agent-visible.
    if (ph != 2 * TSZ - 1 && tid == 0)
      __hip_atomic_store(own + jc, (unsigned)(ph + 1),
                         __ATOMIC_RELEASE, __HIP_MEMORY_SCOPE_AGENT);
  }
}

extern "C" void kernel_launch(void* const* d_in, const int* in_sizes, int n_in,
                              void* d_out, int out_size, void* d_ws, size_t ws_size,
                              hipStream_t stream) {
  (void)in_sizes; (void)n_in; (void)out_size; (void)ws_size;
  const float* x0   = (const float*)d_in[0];
  const float* h0   = (const float*)d_in[1];
  const float* c0   = (const float*)d_in[2];
  const float* Wih  = (const float*)d_in[3];
  const float* Whh  = (const float*)d_in[4];
  const float* b_ih = (const float*)d_in[5];
  const float* b_hh = (const float*)d_in[6];
  const float* u_ih = (const float*)d_in[7];
  const float* u_hh = (const float*)d_in[8];
  float* out = (float*)d_out;

  char* ws = (char*)d_ws;
  size_t off = 0;
  auto alloc = [&](size_t bytes) -> void* {
    void* p = ws + off;
    off = (off + bytes + 255) & ~(size_t)255;
    return p;
  };
  _Float16* wcomb  = (_Float16*)alloc((size_t)2 * 4096 * 2048 * 2);
  float*    vpart  = (float*)alloc((size_t)4 * 16 * 1024 * 4);
  float*    vraw   = (float*)alloc((size_t)4 * 1024 * 4);
  float*    wv     = (float*)alloc((size_t)4 * 4096 * 4);
  float*    invsig = (float*)alloc(16);
  float*    bias   = (float*)alloc((size_t)2 * 4096 * 4);
  _Float16* Xinit  = (_Float16*)alloc((size_t)262144 * 2);
  _Float16* Hb[2][2];
  for (int a = 0; a < 2; ++a)
    for (int p = 0; p < 2; ++p)
      Hb[a][p] = (_Float16*)alloc((size_t)262144 * 2);
  float* Cb[2];
  Cb[0] = (float*)alloc((size_t)262144 * 4);
  Cb[1] = (float*)alloc((size_t)262144 * 4);
  unsigned* arr = (unsigned*)alloc(4 * 64 * sizeof(unsigned));

  prep_vraw1<<<256, 256, 0, stream>>>(Wih, Whh, u_ih, u_hh, vpart);
  prep_vraw2<<<16, 256, 0, stream>>>(vpart, vraw);
  prep_wv<<<dim3(1024, 4), 256, 0, stream>>>(Wih, Whh, vraw, wv);
  prep_sig<<<4, 256, 0, stream>>>(vraw, wv, invsig);
  prep_wcomb<<<16384, 256, 0, stream>>>(Wih, Whh, invsig, wcomb);
  prep_bias<<<32, 256, 0, stream>>>(b_ih, b_hh, bias);
  prep_init<<<1024, 256, 0, stream>>>(x0, h0, c0, Xinit, Hb[0][0], Hb[1][0], Cb[0], Cb[1]);
  hipMemsetAsync(arr, 0, 4 * 64 * sizeof(unsigned), stream);

  _Float16* W0 = wcomb;
  _Float16* W1 = wcomb + (size_t)4096 * 2048;

  lstm_persist<<<dim3(NBLK), dim3(256), 0, stream>>>(
      W0, W1, bias, Xinit, Hb[0][0], Hb[0][1], Hb[1][0], Hb[1][1],
      Cb[0], Cb[1], out, arr);
}